// Round 5
// baseline (139.610 us; speedup 1.0000x reference)
//
#include <hip/hip_runtime.h>
#include <cstdint>

#define T_DIM 1000
#define B_DIM 64
#define C_DIM 256
#define L_DIM 100
#define S_DIM (2 * L_DIM + 1) /* 201 */
#define CH 32                 /* steps per chunk */
#define NPROD 7               /* producer waves (block = 8 waves) */
#define RPW 5                 /* ceil(CH/NPROD) rows per producer wave */
#define MEAN_BLOCKS 256       /* 64 b x 4 ; each block covers 2 of 8 T-slices */
#define MEAN_ROWS 125

// DPP cross-lane (VALU-rate). wave_shr:1=0x138, row_shr:n=0x110|n,
// row_bcast:15=0x142, row_bcast:31=0x143. bound_ctrl=true -> invalid lanes read 0.
#define DPP_I(x, ctrl) __builtin_amdgcn_update_dpp(0, (x), (ctrl), 0xF, 0xF, true)
#define DPP_F(x, ctrl) __int_as_float(DPP_I(__float_as_int(x), (ctrl)))

// Empty inline-asm pin (producer only).
#define PIN(x) asm volatile("" : "+v"(x))

// R4: the consumer's LDS reads are inline-asm ds_read_b32 with MANUAL counted
// lgkmcnt waits. R1 (PIN), R2 (dataflow rotation), R3 (sched_group_barrier)
// all failed to create prefetch distance -- the scheduler sank every
// compiler-visible ds_read to point-of-use (VGPR stayed 52, dur stayed 57us).
// Volatile asm preserves program order among asm ops; the waitcnt pass does
// not track asm reads; sched_barrier(0) after each wait stops VALU hoisting
// across it (guide rule #18).
#define DSR(dst, addr, OFF) \
    asm volatile("ds_read_b32 %0, %1 offset:" OFF : "=v"(dst) : "v"(addr))
#define ISS(s, OFF) do { DSR(pb##s, apb, OFF); DSR(qa##s, aq1, OFF); DSR(qb##s, aq3, OFF); } while (0)
#define W(N) do { asm volatile("s_waitcnt lgkmcnt(" N ")"); __builtin_amdgcn_sched_barrier(0); } while (0)
#define STP(s) step(pb##s, qa##s, qb##s)

// Wave-wide max of non-negative values; exact, order-independent.
__device__ __forceinline__ float wave_max_dpp(float x) {
    x = fmaxf(x, DPP_F(x, 0x111)); // row_shr:1
    x = fmaxf(x, DPP_F(x, 0x112)); // row_shr:2
    x = fmaxf(x, DPP_F(x, 0x114)); // row_shr:4
    x = fmaxf(x, DPP_F(x, 0x118)); // row_shr:8
    x = fmaxf(x, DPP_F(x, 0x142)); // row_bcast:15
    x = fmaxf(x, DPP_F(x, 0x143)); // row_bcast:31 -> lane 63 has wave max
    return __int_as_float(__builtin_amdgcn_readlane(__float_as_int(x), 63));
}

// Fused kernel, 512-thread blocks:
//   blocks [0,B): CTC alpha recursion.
//     wave 0  = consumer: serial chain; 5-deep inline-asm LDS pipeline
//               (15 ds_read in flight = lgkmcnt cap). Step d waits
//               lgkmcnt(12) -> its own 3 reads done; issues d+5's reads
//               after computing. Read-to-use distance ~5 steps ~ 125cy,
//               covering the ~120cy LDS latency that dominated (134cy/step
//               measured at baseline).
//     waves 1-7 = producers: per chunk, each loads 5 full rows COALESCED,
//               pins, exps the whole row, stores to ping-pong LDS.
//   blocks [B, B+256): mean-over-time exp(log_probs) -> atomicAdd ws_mean.
__global__ __launch_bounds__(512, 1) void ctc_fused(
        const float* __restrict__ lp,       // (T,B,C)
        const int* __restrict__ tgt,        // (B*L,)
        const int* __restrict__ il,         // (B,)
        const int* __restrict__ tl,         // (B,)
        float* __restrict__ ws_mean,        // (B,C) zero-initialized
        float* __restrict__ ws_loss) {      // (B,)
    const int blk = blockIdx.x;
    const uint32_t rstride = B_DIM * C_DIM;

    if (blk >= B_DIM) {
        // ---- mean_probs pass: block = (b, slicepair); thread = (half, c) ----
        const int mb = blk - B_DIM;
        const int b = mb >> 2;
        const int half = threadIdx.x >> 8;         // 0/1
        const int c = threadIdx.x & 255;
        const int slice = ((mb & 3) << 1) + half;  // 0..7, 125 rows each
        const float* p = lp + (size_t)b * C_DIM + c + (size_t)(slice * MEAN_ROWS) * rstride;
        float s0 = 0.f, s1 = 0.f, s2 = 0.f, s3 = 0.f, s4 = 0.f;
        for (int t = 0; t < MEAN_ROWS; t += 5) {
            s0 += __expf(p[(size_t)(t + 0) * rstride]);
            s1 += __expf(p[(size_t)(t + 1) * rstride]);
            s2 += __expf(p[(size_t)(t + 2) * rstride]);
            s3 += __expf(p[(size_t)(t + 3) * rstride]);
            s4 += __expf(p[(size_t)(t + 4) * rstride]);
        }
        atomicAdd(&ws_mean[b * C_DIM + c], (s0 + s1 + s2 + s3 + s4) * (1.0f / T_DIM));
        return;
    }

    // ---- CTC pass ----
    __shared__ __align__(16) float rows[2][CH][C_DIM]; // exp'd rows, 64 KB

    const int tid = threadIdx.x;
    const int lane = tid & 63;
    const int wave = tid >> 6;
    const int b = blk;
    const int* trow = tgt + b * L_DIM;
    const int ilen = il[b];
    const int tlen = tl[b];

    const int i1 = 2 * lane;
    const int i3 = 2 * lane + 1;
    const int c1 = (i1 < L_DIM) ? trow[i1] : 0;
    const int c3 = (i3 < L_DIM) ? trow[i3] : 0;
    const int c1m = (i1 >= 1 && i1 - 1 < L_DIM) ? trow[i1 - 1] : -1;
    const float m1 = ((i1 >= 1) && (c1 != c1m)) ? 1.0f : 0.0f;
    const float m3 = (c3 != c1) ? 1.0f : 0.0f;

    // invalid states (s >= S) must be zeroed at each renorm (R2 lesson)
    const float f0 = (4 * lane + 0 < S_DIM) ? 1.0f : 0.0f;
    const float f1 = (4 * lane + 1 < S_DIM) ? 1.0f : 0.0f;
    const float f2 = (4 * lane + 2 < S_DIM) ? 1.0f : 0.0f;
    const float f3 = (4 * lane + 3 < S_DIM) ? 1.0f : 0.0f;

    const float* base = lp + (size_t)b * C_DIM;

    // t=0 init (bit-identical to R5..R9)
    float a0 = 0.f, a1 = 0.f, a2 = 0.f, a3 = 0.f;
    {
        float i0 = __expf(base[0]);
        float i1v = __expf(base[c1]);
        if (lane == 0 && wave == 0) { a0 = i0; a1 = i1v; }
    }
    float ls = 0.f;

    // producer: 5 coalesced row loads (phase 1), pin, exp + LDS store (phase 2)
    auto produce = [&](int cc) {
        const int p = cc & 1;
        const int tstart = 1 + cc * CH;
        float4 v[RPW];
#pragma unroll
        for (int k = 0; k < RPW; ++k) {
            const int d = (wave - 1) + NPROD * k;
            if (d < CH) {
                int t = tstart + d; t = (t < ilen) ? t : (ilen - 1);
                v[k] = *(const float4*)(base + (size_t)t * rstride + (lane << 2));
            }
        }
#pragma unroll
        for (int k = 0; k < RPW; ++k) {
            const int d = (wave - 1) + NPROD * k;
            if (d < CH) { PIN(v[k].x); PIN(v[k].y); PIN(v[k].z); PIN(v[k].w); }
        }
#pragma unroll
        for (int k = 0; k < RPW; ++k) {
            const int d = (wave - 1) + NPROD * k;
            if (d < CH) {
                float4 e;
                e.x = __expf(v[k].x); e.y = __expf(v[k].y);
                e.z = __expf(v[k].z); e.w = __expf(v[k].w);
                *(float4*)&rows[p][d][lane << 2] = e;
            }
        }
    };

    // consumer step: inputs are already exp'd (bitwise-identical to computing
    // __expf locally -- same v_exp_f32 on same inputs). absmax must stay 96.0.
    auto step = [&](float pb, float p1e, float p3e) {
        const float p3 = DPP_F(a3, 0x138); // prev lane's a3; lane0 -> 0
        const float a01 = a0 + a1;
        const float n0 = (a0 + p3) * pb;
        const float n1 = fmaf(m1, p3, a01) * p1e;
        const float n2 = (a2 + a1) * pb;
        const float n3 = (fmaf(m3, a1, a2) + a3) * p3e;
        a0 = n0; a1 = n1; a2 = n2; a3 = n3;
    };

#define RENORM() do {                                                       \
        a0 *= f0; a1 *= f1; a2 *= f2; a3 *= f3;                             \
        const float mx = wave_max_dpp(fmaxf(fmaxf(a0, a1), fmaxf(a2, a3))); \
        const float inv = __builtin_amdgcn_rcpf(mx);                        \
        ls -= __logf(inv);                                                  \
        a0 *= inv; a1 *= inv; a2 *= inv; a3 *= inv;                         \
    } while (0)

    // consume chunk cc; renorms after d=7,15,23,31: EXACTLY the baseline
    // renorm set (last at t=992 for T=1000; tail chunk has none).
    // Steady path: explicit 32-step asm pipeline, slot = d%5.
    auto consume = [&](int cc) {
        const int p = cc & 1;
        const int tstart = 1 + cc * CH;
        if (tstart + CH <= ilen) {
            const uint32_t lbase =
                (uint32_t)(uintptr_t)(&rows[0][0][0]) + (uint32_t)(p * (CH * C_DIM * 4));
            uint32_t apb = lbase;                          // rows[p][d][0]
            uint32_t aq1 = lbase + ((uint32_t)c1 << 2);    // rows[p][d][c1]
            uint32_t aq3 = lbase + ((uint32_t)c3 << 2);    // rows[p][d][c3]
            float pb0, pb1, pb2, pb3, pb4;
            float qa0, qa1, qa2, qa3, qa4;
            float qb0, qb1, qb2, qb3, qb4;
            // prologue: steps 0..4 in flight (15 DS ops = lgkmcnt cap)
            ISS(0, "0"); ISS(1, "1024"); ISS(2, "2048"); ISS(3, "3072"); ISS(4, "4096");
            W("12"); STP(0); ISS(0, "5120");                 // d=0
            W("12"); STP(1); ISS(1, "6144");                 // d=1
            W("12"); STP(2); ISS(2, "7168");                 // d=2
            W("12"); STP(3); ISS(3, "8192");                 // d=3
            W("12"); STP(4); ISS(4, "9216");                 // d=4
            W("12"); STP(0); ISS(0, "10240");                // d=5
            W("12"); STP(1); ISS(1, "11264");                // d=6
            W("12"); STP(2); ISS(2, "12288"); RENORM();      // d=7
            W("12"); STP(3); ISS(3, "13312");                // d=8
            W("12"); STP(4); ISS(4, "14336");                // d=9
            W("12"); STP(0); ISS(0, "15360");                // d=10
            W("12"); STP(1); ISS(1, "16384");                // d=11
            W("12"); STP(2); ISS(2, "17408");                // d=12
            W("12"); STP(3); ISS(3, "18432");                // d=13
            W("12"); STP(4); ISS(4, "19456");                // d=14
            W("12"); STP(0); ISS(0, "20480"); RENORM();      // d=15
            W("12"); STP(1); ISS(1, "21504");                // d=16
            W("12"); STP(2); ISS(2, "22528");                // d=17
            W("12"); STP(3); ISS(3, "23552");                // d=18
            W("12"); STP(4); ISS(4, "24576");                // d=19
            W("12"); STP(0); ISS(0, "25600");                // d=20
            W("12"); STP(1); ISS(1, "26624");                // d=21
            W("12"); STP(2); ISS(2, "27648");                // d=22
            W("12"); STP(3); ISS(3, "28672"); RENORM();      // d=23
            W("12"); STP(4); ISS(4, "29696");                // d=24
            W("12"); STP(0); ISS(0, "30720");                // d=25
            W("12"); STP(1); ISS(1, "31744");                // d=26 (issues d=31)
            W("12"); STP(2);                                 // d=27
            W("9");  STP(3);                                 // d=28
            W("6");  STP(4);                                 // d=29
            W("3");  STP(0);                                 // d=30
            W("0");  STP(1); RENORM();                       // d=31
        } else {
            // tail chunk (7 steps for T=1000): baseline point-of-use form
#pragma unroll
            for (int d = 0; d < CH; ++d) {
                if (tstart + d < ilen) {
                    step(rows[p][d][0], rows[p][d][c1], rows[p][d][c3]);
                    if ((d & 7) == 7) RENORM();
                }
            }
        }
    };

    const int nchunks = (ilen - 1 + CH - 1) / CH;
    if (wave != 0) produce(0);
    __syncthreads();
    if (wave == 0) __builtin_amdgcn_s_setprio(1); // consumer is the critical chain
    for (int c = 0; c < nchunks; ++c) {
        if (wave != 0) produce(c + 1); // other parity; last iter clamped junk, never read
        else consume(c);
        __syncthreads();
    }
    if (wave == 0) __builtin_amdgcn_s_setprio(0);
#undef RENORM

    if (wave != 0) return;

    // final: ll = log(alpha[2tl] + alpha[2tl-1]) + ls   (consumer wave only)
    const int s_hi = 2 * tlen;
    const int s_lo = 2 * tlen - 1;
    const int slot_hi = s_hi & 3, lane_hi = min(s_hi >> 2, 63);
    const int slot_lo = s_lo & 3, lane_lo = min(s_lo >> 2, 63);
    float ch = (slot_hi == 0) ? a0 : (slot_hi == 1) ? a1 : (slot_hi == 2) ? a2 : a3;
    float cl = (slot_lo == 0) ? a0 : (slot_lo == 1) ? a1 : (slot_lo == 2) ? a2 : a3;
    const float vh = __shfl(ch, lane_hi, 64);
    const float vl = __shfl(cl, lane_lo, 64);
    if (lane == 0) {
        const float s = vh + vl;
        const float loss = (s > 0.f) ? -(__logf(s) + ls) : 0.0f; // zero_infinity
        ws_loss[b] = loss;
    }
}

// out = (sum_j focal_j / (B*L)) * (sum_b loss_b / B)
__global__ __launch_bounds__(256) void ctc_finalize(
        const float* __restrict__ ws_mean, const float* __restrict__ ws_loss,
        const int* __restrict__ tgt, float* __restrict__ out) {
    const int tid = threadIdx.x;
    float fsum = 0.f;
#pragma unroll
    for (int k = 0; k < (B_DIM * L_DIM) / 256; ++k) {
        const int j = tid + k * 256;
        const int b = j / L_DIM;
        const int c = tgt[j];
        const float p = ws_mean[b * C_DIM + c];
        const float w = 1.0f - p;
        fsum += w * w;
    }
    float lsum = (tid < B_DIM) ? ws_loss[tid] : 0.f;
#pragma unroll
    for (int off = 32; off > 0; off >>= 1) {
        fsum += __shfl_down(fsum, off, 64);
        lsum += __shfl_down(lsum, off, 64);
    }
    __shared__ float sf[4], sl[4];
    const int w = tid >> 6;
    if ((tid & 63) == 0) { sf[w] = fsum; sl[w] = lsum; }
    __syncthreads();
    if (tid == 0) {
        const float F = sf[0] + sf[1] + sf[2] + sf[3];
        const float Lo = sl[0] + sl[1] + sl[2] + sl[3];
        out[0] = (F / (float)(B_DIM * L_DIM)) * (Lo / (float)B_DIM);
    }
}

extern "C" void kernel_launch(void* const* d_in, const int* in_sizes, int n_in,
                              void* d_out, int out_size, void* d_ws, size_t ws_size,
                              hipStream_t stream) {
    const float* lp = (const float*)d_in[0];
    const int* tgt = (const int*)d_in[1];
    const int* il = (const int*)d_in[2];
    const int* tl = (const int*)d_in[3];
    float* ws_mean = (float*)d_ws;               // B*C floats (atomicAdd target)
    float* ws_loss = ws_mean + B_DIM * C_DIM;    // B floats

    hipMemsetAsync(ws_mean, 0, B_DIM * C_DIM * sizeof(float), stream);
    ctc_fused<<<dim3(B_DIM + MEAN_BLOCKS), dim3(512), 0, stream>>>(
        lp, tgt, il, tl, ws_mean, ws_loss);
    ctc_finalize<<<dim3(1), dim3(256), 0, stream>>>(ws_mean, ws_loss, tgt, (float*)d_out);
}

// Round 6
// 136.883 us; speedup vs baseline: 1.0199x; 1.0199x over previous
//
#include <hip/hip_runtime.h>
#include <cstdint>

#define T_DIM 1000
#define B_DIM 64
#define C_DIM 256
#define L_DIM 100
#define S_DIM (2 * L_DIM + 1) /* 201 */
#define CH 32                 /* steps per chunk */
#define NPROD 7               /* producer waves (block = 8 waves) */
#define RPW 5                 /* ceil(CH/NPROD) rows per producer wave */
#define MEAN_BLOCKS 192       /* 64 b x 3 T-slices; grid = 64+192 = 256 = #CUs */

// DPP cross-lane (VALU-rate). wave_shr:1=0x138, row_shr:n=0x110|n,
// row_bcast:15=0x142, row_bcast:31=0x143. bound_ctrl=true -> invalid lanes read 0.
#define DPP_I(x, ctrl) __builtin_amdgcn_update_dpp(0, (x), (ctrl), 0xF, 0xF, true)
#define DPP_F(x, ctrl) __int_as_float(DPP_I(__float_as_int(x), (ctrl)))

// Empty inline-asm pin (producer only).
#define PIN(x) asm volatile("" : "+v"(x))

// Consumer LDS reads: inline-asm ds_read_b32 + manual counted lgkmcnt waits
// (R4). R1 (PIN), R2 (dataflow rotation), R3 (sched_group_barrier) all failed
// to create prefetch distance at source level. R5 result: even THIS pipeline
// didn't change dur -> consumer LDS latency was never the bottleneck; kept
// because it is proven-correct and at worst neutral.
#define DSR(dst, addr, OFF) \
    asm volatile("ds_read_b32 %0, %1 offset:" OFF : "=v"(dst) : "v"(addr))
#define ISS(s, OFF) do { DSR(pb##s, apb, OFF); DSR(qa##s, aq1, OFF); DSR(qb##s, aq3, OFF); } while (0)
#define W(N) do { asm volatile("s_waitcnt lgkmcnt(" N ")"); __builtin_amdgcn_sched_barrier(0); } while (0)
#define STP(s) step(pb##s, qa##s, qb##s)

// Wave-wide max of non-negative values; exact, order-independent.
__device__ __forceinline__ float wave_max_dpp(float x) {
    x = fmaxf(x, DPP_F(x, 0x111)); // row_shr:1
    x = fmaxf(x, DPP_F(x, 0x112)); // row_shr:2
    x = fmaxf(x, DPP_F(x, 0x114)); // row_shr:4
    x = fmaxf(x, DPP_F(x, 0x118)); // row_shr:8
    x = fmaxf(x, DPP_F(x, 0x142)); // row_bcast:15
    x = fmaxf(x, DPP_F(x, 0x143)); // row_bcast:31 -> lane 63 has wave max
    return __int_as_float(__builtin_amdgcn_readlane(__float_as_int(x), 63));
}

// Fused kernel, 512-thread blocks. R5 change: grid is EXACTLY 256 blocks
// (= #CUs). The old 320-block grid round-robin-wrapped the last 64 mean
// blocks onto the same CUs as the 64 CTC blocks (by construction: blocks
// 256..319 land on CU-slots 0..7 of each XCD, same as blocks 0..63), so
// every CTC consumer wave shared its SIMD with expf-spamming mean waves
// for the whole kernel. 256 blocks -> 1 block/CU, zero co-residency.
//   blocks [0,B): CTC alpha recursion (UNCHANGED from R4 -> bit-identical).
//   blocks [B, B+192): mean-over-time exp(log_probs) -> atomicAdd ws_mean.
//     block = (b, slice of T): slices {335,335,330} rows; 512 threads =
//     2 halves x 256 c; half-counts {170,165} / {165,165} (multiples of 5).
__global__ __launch_bounds__(512, 1) void ctc_fused(
        const float* __restrict__ lp,       // (T,B,C)
        const int* __restrict__ tgt,        // (B*L,)
        const int* __restrict__ il,         // (B,)
        const int* __restrict__ tl,         // (B,)
        float* __restrict__ ws_mean,        // (B,C) zero-initialized
        float* __restrict__ ws_loss) {      // (B,)
    const int blk = blockIdx.x;
    const uint32_t rstride = B_DIM * C_DIM;

    if (blk >= B_DIM) {
        // ---- mean_probs pass ----
        const int mb = blk - B_DIM;
        const int b = mb / 3;
        const int slice = mb % 3;                  // 0..2
        const int half = threadIdx.x >> 8;         // 0/1
        const int c = threadIdx.x & 255;
        const int h0 = (slice < 2) ? 170 : 165;    // half-0 row count
        const int scount = (slice < 2) ? 335 : 330;
        const int start = slice * 335 + (half ? h0 : 0);
        const int cnt = half ? (scount - h0) : h0; // 165 or 170, %5 == 0
        const float* p = lp + (size_t)b * C_DIM + c + (size_t)start * rstride;
        float s0 = 0.f, s1 = 0.f, s2 = 0.f, s3 = 0.f, s4 = 0.f;
        for (int t = 0; t < cnt; t += 5) {
            s0 += __expf(p[(size_t)(t + 0) * rstride]);
            s1 += __expf(p[(size_t)(t + 1) * rstride]);
            s2 += __expf(p[(size_t)(t + 2) * rstride]);
            s3 += __expf(p[(size_t)(t + 3) * rstride]);
            s4 += __expf(p[(size_t)(t + 4) * rstride]);
        }
        atomicAdd(&ws_mean[b * C_DIM + c], (s0 + s1 + s2 + s3 + s4) * (1.0f / T_DIM));
        return;
    }

    // ---- CTC pass (unchanged from R4) ----
    __shared__ __align__(16) float rows[2][CH][C_DIM]; // exp'd rows, 64 KB

    const int tid = threadIdx.x;
    const int lane = tid & 63;
    const int wave = tid >> 6;
    const int b = blk;
    const int* trow = tgt + b * L_DIM;
    const int ilen = il[b];
    const int tlen = tl[b];

    const int i1 = 2 * lane;
    const int i3 = 2 * lane + 1;
    const int c1 = (i1 < L_DIM) ? trow[i1] : 0;
    const int c3 = (i3 < L_DIM) ? trow[i3] : 0;
    const int c1m = (i1 >= 1 && i1 - 1 < L_DIM) ? trow[i1 - 1] : -1;
    const float m1 = ((i1 >= 1) && (c1 != c1m)) ? 1.0f : 0.0f;
    const float m3 = (c3 != c1) ? 1.0f : 0.0f;

    // invalid states (s >= S) must be zeroed at each renorm (R2 lesson)
    const float f0 = (4 * lane + 0 < S_DIM) ? 1.0f : 0.0f;
    const float f1 = (4 * lane + 1 < S_DIM) ? 1.0f : 0.0f;
    const float f2 = (4 * lane + 2 < S_DIM) ? 1.0f : 0.0f;
    const float f3 = (4 * lane + 3 < S_DIM) ? 1.0f : 0.0f;

    const float* base = lp + (size_t)b * C_DIM;

    // t=0 init (bit-identical to R5..R9)
    float a0 = 0.f, a1 = 0.f, a2 = 0.f, a3 = 0.f;
    {
        float i0 = __expf(base[0]);
        float i1v = __expf(base[c1]);
        if (lane == 0 && wave == 0) { a0 = i0; a1 = i1v; }
    }
    float ls = 0.f;

    // producer: 5 coalesced row loads (phase 1), pin, exp + LDS store (phase 2)
    auto produce = [&](int cc) {
        const int p = cc & 1;
        const int tstart = 1 + cc * CH;
        float4 v[RPW];
#pragma unroll
        for (int k = 0; k < RPW; ++k) {
            const int d = (wave - 1) + NPROD * k;
            if (d < CH) {
                int t = tstart + d; t = (t < ilen) ? t : (ilen - 1);
                v[k] = *(const float4*)(base + (size_t)t * rstride + (lane << 2));
            }
        }
#pragma unroll
        for (int k = 0; k < RPW; ++k) {
            const int d = (wave - 1) + NPROD * k;
            if (d < CH) { PIN(v[k].x); PIN(v[k].y); PIN(v[k].z); PIN(v[k].w); }
        }
#pragma unroll
        for (int k = 0; k < RPW; ++k) {
            const int d = (wave - 1) + NPROD * k;
            if (d < CH) {
                float4 e;
                e.x = __expf(v[k].x); e.y = __expf(v[k].y);
                e.z = __expf(v[k].z); e.w = __expf(v[k].w);
                *(float4*)&rows[p][d][lane << 2] = e;
            }
        }
    };

    // consumer step: inputs are already exp'd (bitwise-identical to computing
    // __expf locally -- same v_exp_f32 on same inputs). absmax must stay 96.0.
    auto step = [&](float pb, float p1e, float p3e) {
        const float p3 = DPP_F(a3, 0x138); // prev lane's a3; lane0 -> 0
        const float a01 = a0 + a1;
        const float n0 = (a0 + p3) * pb;
        const float n1 = fmaf(m1, p3, a01) * p1e;
        const float n2 = (a2 + a1) * pb;
        const float n3 = (fmaf(m3, a1, a2) + a3) * p3e;
        a0 = n0; a1 = n1; a2 = n2; a3 = n3;
    };

#define RENORM() do {                                                       \
        a0 *= f0; a1 *= f1; a2 *= f2; a3 *= f3;                             \
        const float mx = wave_max_dpp(fmaxf(fmaxf(a0, a1), fmaxf(a2, a3))); \
        const float inv = __builtin_amdgcn_rcpf(mx);                        \
        ls -= __logf(inv);                                                  \
        a0 *= inv; a1 *= inv; a2 *= inv; a3 *= inv;                         \
    } while (0)

    // consume chunk cc; renorms after d=7,15,23,31: EXACTLY the baseline
    // renorm set (last at t=992 for T=1000; tail chunk has none).
    // Steady path: explicit 32-step asm pipeline, slot = d%5.
    auto consume = [&](int cc) {
        const int p = cc & 1;
        const int tstart = 1 + cc * CH;
        if (tstart + CH <= ilen) {
            const uint32_t lbase =
                (uint32_t)(uintptr_t)(&rows[0][0][0]) + (uint32_t)(p * (CH * C_DIM * 4));
            uint32_t apb = lbase;                          // rows[p][d][0]
            uint32_t aq1 = lbase + ((uint32_t)c1 << 2);    // rows[p][d][c1]
            uint32_t aq3 = lbase + ((uint32_t)c3 << 2);    // rows[p][d][c3]
            float pb0, pb1, pb2, pb3, pb4;
            float qa0, qa1, qa2, qa3, qa4;
            float qb0, qb1, qb2, qb3, qb4;
            // prologue: steps 0..4 in flight (15 DS ops = lgkmcnt cap)
            ISS(0, "0"); ISS(1, "1024"); ISS(2, "2048"); ISS(3, "3072"); ISS(4, "4096");
            W("12"); STP(0); ISS(0, "5120");                 // d=0
            W("12"); STP(1); ISS(1, "6144");                 // d=1
            W("12"); STP(2); ISS(2, "7168");                 // d=2
            W("12"); STP(3); ISS(3, "8192");                 // d=3
            W("12"); STP(4); ISS(4, "9216");                 // d=4
            W("12"); STP(0); ISS(0, "10240");                // d=5
            W("12"); STP(1); ISS(1, "11264");                // d=6
            W("12"); STP(2); ISS(2, "12288"); RENORM();      // d=7
            W("12"); STP(3); ISS(3, "13312");                // d=8
            W("12"); STP(4); ISS(4, "14336");                // d=9
            W("12"); STP(0); ISS(0, "15360");                // d=10
            W("12"); STP(1); ISS(1, "16384");                // d=11
            W("12"); STP(2); ISS(2, "17408");                // d=12
            W("12"); STP(3); ISS(3, "18432");                // d=13
            W("12"); STP(4); ISS(4, "19456");                // d=14
            W("12"); STP(0); ISS(0, "20480"); RENORM();      // d=15
            W("12"); STP(1); ISS(1, "21504");                // d=16
            W("12"); STP(2); ISS(2, "22528");                // d=17
            W("12"); STP(3); ISS(3, "23552");                // d=18
            W("12"); STP(4); ISS(4, "24576");                // d=19
            W("12"); STP(0); ISS(0, "25600");                // d=20
            W("12"); STP(1); ISS(1, "26624");                // d=21
            W("12"); STP(2); ISS(2, "27648");                // d=22
            W("12"); STP(3); ISS(3, "28672"); RENORM();      // d=23
            W("12"); STP(4); ISS(4, "29696");                // d=24
            W("12"); STP(0); ISS(0, "30720");                // d=25
            W("12"); STP(1); ISS(1, "31744");                // d=26 (issues d=31)
            W("12"); STP(2);                                 // d=27
            W("9");  STP(3);                                 // d=28
            W("6");  STP(4);                                 // d=29
            W("3");  STP(0);                                 // d=30
            W("0");  STP(1); RENORM();                       // d=31
        } else {
            // tail chunk (7 steps for T=1000): baseline point-of-use form
#pragma unroll
            for (int d = 0; d < CH; ++d) {
                if (tstart + d < ilen) {
                    step(rows[p][d][0], rows[p][d][c1], rows[p][d][c3]);
                    if ((d & 7) == 7) RENORM();
                }
            }
        }
    };

    const int nchunks = (ilen - 1 + CH - 1) / CH;
    if (wave != 0) produce(0);
    __syncthreads();
    if (wave == 0) __builtin_amdgcn_s_setprio(1); // consumer is the critical chain
    for (int c = 0; c < nchunks; ++c) {
        if (wave != 0) produce(c + 1); // other parity; last iter clamped junk, never read
        else consume(c);
        __syncthreads();
    }
    if (wave == 0) __builtin_amdgcn_s_setprio(0);
#undef RENORM

    if (wave != 0) return;

    // final: ll = log(alpha[2tl] + alpha[2tl-1]) + ls   (consumer wave only)
    const int s_hi = 2 * tlen;
    const int s_lo = 2 * tlen - 1;
    const int slot_hi = s_hi & 3, lane_hi = min(s_hi >> 2, 63);
    const int slot_lo = s_lo & 3, lane_lo = min(s_lo >> 2, 63);
    float ch = (slot_hi == 0) ? a0 : (slot_hi == 1) ? a1 : (slot_hi == 2) ? a2 : a3;
    float cl = (slot_lo == 0) ? a0 : (slot_lo == 1) ? a1 : (slot_lo == 2) ? a2 : a3;
    const float vh = __shfl(ch, lane_hi, 64);
    const float vl = __shfl(cl, lane_lo, 64);
    if (lane == 0) {
        const float s = vh + vl;
        const float loss = (s > 0.f) ? -(__logf(s) + ls) : 0.0f; // zero_infinity
        ws_loss[b] = loss;
    }
}

// out = (sum_j focal_j / (B*L)) * (sum_b loss_b / B)
__global__ __launch_bounds__(256) void ctc_finalize(
        const float* __restrict__ ws_mean, const float* __restrict__ ws_loss,
        const int* __restrict__ tgt, float* __restrict__ out) {
    const int tid = threadIdx.x;
    float fsum = 0.f;
#pragma unroll
    for (int k = 0; k < (B_DIM * L_DIM) / 256; ++k) {
        const int j = tid + k * 256;
        const int b = j / L_DIM;
        const int c = tgt[j];
        const float p = ws_mean[b * C_DIM + c];
        const float w = 1.0f - p;
        fsum += w * w;
    }
    float lsum = (tid < B_DIM) ? ws_loss[tid] : 0.f;
#pragma unroll
    for (int off = 32; off > 0; off >>= 1) {
        fsum += __shfl_down(fsum, off, 64);
        lsum += __shfl_down(lsum, off, 64);
    }
    __shared__ float sf[4], sl[4];
    const int w = tid >> 6;
    if ((tid & 63) == 0) { sf[w] = fsum; sl[w] = lsum; }
    __syncthreads();
    if (tid == 0) {
        const float F = sf[0] + sf[1] + sf[2] + sf[3];
        const float Lo = sl[0] + sl[1] + sl[2] + sl[3];
        out[0] = (F / (float)(B_DIM * L_DIM)) * (Lo / (float)B_DIM);
    }
}

extern "C" void kernel_launch(void* const* d_in, const int* in_sizes, int n_in,
                              void* d_out, int out_size, void* d_ws, size_t ws_size,
                              hipStream_t stream) {
    const float* lp = (const float*)d_in[0];
    const int* tgt = (const int*)d_in[1];
    const int* il = (const int*)d_in[2];
    const int* tl = (const int*)d_in[3];
    float* ws_mean = (float*)d_ws;               // B*C floats (atomicAdd target)
    float* ws_loss = ws_mean + B_DIM * C_DIM;    // B floats

    hipMemsetAsync(ws_mean, 0, B_DIM * C_DIM * sizeof(float), stream);
    ctc_fused<<<dim3(B_DIM + MEAN_BLOCKS), dim3(512), 0, stream>>>(
        lp, tgt, il, tl, ws_mean, ws_loss);
    ctc_finalize<<<dim3(1), dim3(256), 0, stream>>>(ws_mean, ws_loss, tgt, (float*)d_out);
}